// Round 2
// baseline (3492.940 us; speedup 1.0000x reference)
//
#include <hip/hip_runtime.h>
#include <math.h>

#define TT 4096
#define BB 8
#define EE 1024
#define HH 8
#define DD 128
#define KK 64        // proj dim per head
#define PHI2 128     // 2K features per head
#define NPROJ 512    // H*K total pre-sincos width
#define CH 128
#define NC 32
#define NROWS 32768
#define EPSV 1e-6f

__device__ __forceinline__ unsigned short f2b(float f) {
  union { float f; unsigned int u; } v; v.f = f;
  unsigned int u = v.u;
  u += 0x7fffu + ((u >> 16) & 1u);
  return (unsigned short)(u >> 16);
}
__device__ __forceinline__ float b2f(unsigned short h) {
  union { float f; unsigned int u; } v; v.u = ((unsigned int)h) << 16;
  return v.f;
}

// ---- Weff[h*64+k][e] = sum_d s4*sigma[h,d]*rm[h,k,d]*W[h*128+d][e]; beff likewise from b.
__global__ __launch_bounds__(256) void weff_kernel(
    const float* __restrict__ rmat, const float* __restrict__ sigma,
    const float* __restrict__ W, const float* __restrict__ bvec,
    float* __restrict__ Weff, float* __restrict__ beff)
{
  __shared__ float rme[64][130];
  __shared__ float Wt[128][130];
  const int et = blockIdx.x;   // e-tile of 128
  const int h  = blockIdx.y;
  const int tid = threadIdx.x;
  const int e0 = et * 128;
  const float s4 = 0.29730177875068026f;  // 128^-0.25

  for (int f = tid; f < 64 * 32; f += 256) {
    int kk = f >> 5, d = (f & 31) * 4;
    float4 rv = *(const float4*)(rmat + ((size_t)(h * 64 + kk)) * 128 + d);
    const float* sg = sigma + h * 128 + d;
    rme[kk][d + 0] = rv.x * sg[0] * s4;
    rme[kk][d + 1] = rv.y * sg[1] * s4;
    rme[kk][d + 2] = rv.z * sg[2] * s4;
    rme[kk][d + 3] = rv.w * sg[3] * s4;
  }
  for (int f = tid; f < 128 * 32; f += 256) {
    int dd = f >> 5, e = (f & 31) * 4;
    *(float4*)&Wt[dd][e] = *(const float4*)(W + ((size_t)(h * 128 + dd)) * EE + e0 + e);
  }
  __syncthreads();
  const int nl = tid >> 2;
  const int el0 = (tid & 3) * 32;
  for (int e = 0; e < 32; ++e) {
    float acc = 0.f;
#pragma unroll
    for (int d = 0; d < 128; ++d)
      acc = fmaf(rme[nl][d], Wt[d][el0 + e], acc);
    Weff[(size_t)(h * 64 + nl) * EE + e0 + el0 + e] = acc;
  }
  if (et == 0 && tid < 64) {
    float acc = 0.f;
    for (int d = 0; d < 128; ++d)
      acc = fmaf(rme[tid][d], bvec[h * 128 + d], acc);
    beff[h * 64 + tid] = acc;
  }
}

// ---------------- GEMM: C[M,N] = A[M,K] @ W[N,K]^T + bias[N], fp32 out
__global__ __launch_bounds__(256) void gemm_nt(
    const float* __restrict__ A, const float* __restrict__ W,
    const float* __restrict__ bias, float* __restrict__ C,
    int M, int N, int Kd)
{
  __shared__ float At[16][132];
  __shared__ float Wt[16][132];
  const int tid = threadIdx.x;
  const int m0 = blockIdx.x * 128, n0 = blockIdx.y * 128;
  const int ty = tid >> 4, tx = tid & 15;
  float acc[8][8];
#pragma unroll
  for (int i = 0; i < 8; ++i)
#pragma unroll
    for (int j = 0; j < 8; ++j) acc[i][j] = 0.f;

  for (int kt = 0; kt < Kd; kt += 16) {
    __syncthreads();
#pragma unroll
    for (int s = 0; s < 2; ++s) {
      int f = tid + s * 256;
      int row = f >> 2, kq = f & 3;
      float4 av = *(const float4*)(A + (size_t)(m0 + row) * Kd + kt + kq * 4);
      At[kq * 4 + 0][row] = av.x; At[kq * 4 + 1][row] = av.y;
      At[kq * 4 + 2][row] = av.z; At[kq * 4 + 3][row] = av.w;
      float4 wv = *(const float4*)(W + (size_t)(n0 + row) * Kd + kt + kq * 4);
      Wt[kq * 4 + 0][row] = wv.x; Wt[kq * 4 + 1][row] = wv.y;
      Wt[kq * 4 + 2][row] = wv.z; Wt[kq * 4 + 3][row] = wv.w;
    }
    __syncthreads();
#pragma unroll
    for (int kk = 0; kk < 16; ++kk) {
      float a[8], b[8];
      *(float4*)&a[0] = *(const float4*)&At[kk][ty * 8];
      *(float4*)&a[4] = *(const float4*)&At[kk][ty * 8 + 4];
      *(float4*)&b[0] = *(const float4*)&Wt[kk][tx * 8];
      *(float4*)&b[4] = *(const float4*)&Wt[kk][tx * 8 + 4];
#pragma unroll
      for (int i = 0; i < 8; ++i)
#pragma unroll
        for (int j = 0; j < 8; ++j)
          acc[i][j] = fmaf(a[i], b[j], acc[i][j]);
    }
  }
  float bv[8];
#pragma unroll
  for (int j = 0; j < 8; ++j) bv[j] = bias[n0 + tx * 8 + j];
#pragma unroll
  for (int i = 0; i < 8; ++i) {
    float* cp = C + (size_t)(m0 + ty * 8 + i) * N + n0 + tx * 8;
    *(float4*)cp = make_float4(acc[i][0] + bv[0], acc[i][1] + bv[1],
                               acc[i][2] + bv[2], acc[i][3] + bv[3]);
    *(float4*)(cp + 4) = make_float4(acc[i][4] + bv[4], acc[i][5] + bv[5],
                                     acc[i][6] + bv[6], acc[i][7] + bv[7]);
  }
}

// ---------------- GEMM variant: fp32 in, bf16 out (for V)
__global__ __launch_bounds__(256) void gemm_nt_b16out(
    const float* __restrict__ A, const float* __restrict__ W,
    const float* __restrict__ bias, unsigned short* __restrict__ C,
    int M, int N, int Kd)
{
  __shared__ float At[16][132];
  __shared__ float Wt[16][132];
  const int tid = threadIdx.x;
  const int m0 = blockIdx.x * 128, n0 = blockIdx.y * 128;
  const int ty = tid >> 4, tx = tid & 15;
  float acc[8][8];
#pragma unroll
  for (int i = 0; i < 8; ++i)
#pragma unroll
    for (int j = 0; j < 8; ++j) acc[i][j] = 0.f;

  for (int kt = 0; kt < Kd; kt += 16) {
    __syncthreads();
#pragma unroll
    for (int s = 0; s < 2; ++s) {
      int f = tid + s * 256;
      int row = f >> 2, kq = f & 3;
      float4 av = *(const float4*)(A + (size_t)(m0 + row) * Kd + kt + kq * 4);
      At[kq * 4 + 0][row] = av.x; At[kq * 4 + 1][row] = av.y;
      At[kq * 4 + 2][row] = av.z; At[kq * 4 + 3][row] = av.w;
      float4 wv = *(const float4*)(W + (size_t)(n0 + row) * Kd + kt + kq * 4);
      Wt[kq * 4 + 0][row] = wv.x; Wt[kq * 4 + 1][row] = wv.y;
      Wt[kq * 4 + 2][row] = wv.z; Wt[kq * 4 + 3][row] = wv.w;
    }
    __syncthreads();
#pragma unroll
    for (int kk = 0; kk < 16; ++kk) {
      float a[8], b[8];
      *(float4*)&a[0] = *(const float4*)&At[kk][ty * 8];
      *(float4*)&a[4] = *(const float4*)&At[kk][ty * 8 + 4];
      *(float4*)&b[0] = *(const float4*)&Wt[kk][tx * 8];
      *(float4*)&b[4] = *(const float4*)&Wt[kk][tx * 8 + 4];
#pragma unroll
      for (int i = 0; i < 8; ++i)
#pragma unroll
        for (int j = 0; j < 8; ++j)
          acc[i][j] = fmaf(a[i], b[j], acc[i][j]);
    }
  }
  float bv[8];
#pragma unroll
  for (int j = 0; j < 8; ++j) bv[j] = bias[n0 + tx * 8 + j];
#pragma unroll
  for (int i = 0; i < 8; ++i) {
    unsigned short* cp = C + (size_t)(m0 + ty * 8 + i) * N + n0 + tx * 8;
    ushort4 o0 = make_ushort4(f2b(acc[i][0] + bv[0]), f2b(acc[i][1] + bv[1]),
                              f2b(acc[i][2] + bv[2]), f2b(acc[i][3] + bv[3]));
    ushort4 o1 = make_ushort4(f2b(acc[i][4] + bv[4]), f2b(acc[i][5] + bv[5]),
                              f2b(acc[i][6] + bv[6]), f2b(acc[i][7] + bv[7]));
    *(ushort4*)cp = o0;
    *(ushort4*)(cp + 4) = o1;
  }
}

// ---------------- GEMM variant: bf16 A, fp32 W/out (final projection)
__global__ __launch_bounds__(256) void gemm_nt_a16(
    const unsigned short* __restrict__ A, const float* __restrict__ W,
    const float* __restrict__ bias, float* __restrict__ C,
    int M, int N, int Kd)
{
  __shared__ float At[16][132];
  __shared__ float Wt[16][132];
  const int tid = threadIdx.x;
  const int m0 = blockIdx.x * 128, n0 = blockIdx.y * 128;
  const int ty = tid >> 4, tx = tid & 15;
  float acc[8][8];
#pragma unroll
  for (int i = 0; i < 8; ++i)
#pragma unroll
    for (int j = 0; j < 8; ++j) acc[i][j] = 0.f;

  for (int kt = 0; kt < Kd; kt += 16) {
    __syncthreads();
#pragma unroll
    for (int s = 0; s < 2; ++s) {
      int f = tid + s * 256;
      int row = f >> 2, kq = f & 3;
      ushort4 av = *(const ushort4*)(A + (size_t)(m0 + row) * Kd + kt + kq * 4);
      At[kq * 4 + 0][row] = b2f(av.x); At[kq * 4 + 1][row] = b2f(av.y);
      At[kq * 4 + 2][row] = b2f(av.z); At[kq * 4 + 3][row] = b2f(av.w);
      float4 wv = *(const float4*)(W + (size_t)(n0 + row) * Kd + kt + kq * 4);
      Wt[kq * 4 + 0][row] = wv.x; Wt[kq * 4 + 1][row] = wv.y;
      Wt[kq * 4 + 2][row] = wv.z; Wt[kq * 4 + 3][row] = wv.w;
    }
    __syncthreads();
#pragma unroll
    for (int kk = 0; kk < 16; ++kk) {
      float a[8], b[8];
      *(float4*)&a[0] = *(const float4*)&At[kk][ty * 8];
      *(float4*)&a[4] = *(const float4*)&At[kk][ty * 8 + 4];
      *(float4*)&b[0] = *(const float4*)&Wt[kk][tx * 8];
      *(float4*)&b[4] = *(const float4*)&Wt[kk][tx * 8 + 4];
#pragma unroll
      for (int i = 0; i < 8; ++i)
#pragma unroll
        for (int j = 0; j < 8; ++j)
          acc[i][j] = fmaf(a[i], b[j], acc[i][j]);
    }
  }
  float bv[8];
#pragma unroll
  for (int j = 0; j < 8; ++j) bv[j] = bias[n0 + tx * 8 + j];
#pragma unroll
  for (int i = 0; i < 8; ++i) {
    float* cp = C + (size_t)(m0 + ty * 8 + i) * N + n0 + tx * 8;
    *(float4*)cp = make_float4(acc[i][0] + bv[0], acc[i][1] + bv[1],
                               acc[i][2] + bv[2], acc[i][3] + bv[3]);
    *(float4*)(cp + 4) = make_float4(acc[i][4] + bv[4], acc[i][5] + bv[5],
                                     acc[i][6] + bv[6], acc[i][7] + bv[7]);
  }
}

// ---------------- pass1: per (c,b,h): S_c[f][d] = sum_j phi_k[j][f]*v[j][d]; z_c[f]
__global__ __launch_bounds__(256) void pass1_kernel(
    const float* __restrict__ Pk, const unsigned short* __restrict__ Vb,
    unsigned short* __restrict__ Sb, float* __restrict__ Z)
{
  __shared__ float kt[16][132];
  __shared__ float vt[16][132];
  const int c = blockIdx.x, b = blockIdx.y, h = blockIdx.z;
  const int tid = threadIdx.x;
  const int ty = tid >> 4, tx = tid & 15;
  float acc[8][8];
#pragma unroll
  for (int i = 0; i < 8; ++i)
#pragma unroll
    for (int j = 0; j < 8; ++j) acc[i][j] = 0.f;
  float zacc[8] = {0.f, 0.f, 0.f, 0.f, 0.f, 0.f, 0.f, 0.f};

  for (int jt = 0; jt < CH; jt += 16) {
    __syncthreads();
    {
      int jj = tid >> 4, q = tid & 15;
      size_t row = (size_t)((c * CH + jt + jj) * BB + b);
      float4 pv = *(const float4*)(Pk + row * NPROJ + h * KK + q * 4);
      float sv, cv;
      sincosf(pv.x, &sv, &cv);
      kt[jj][q * 4 + 0] = sv * 0.125f; kt[jj][64 + q * 4 + 0] = cv * 0.125f;
      sincosf(pv.y, &sv, &cv);
      kt[jj][q * 4 + 1] = sv * 0.125f; kt[jj][64 + q * 4 + 1] = cv * 0.125f;
      sincosf(pv.z, &sv, &cv);
      kt[jj][q * 4 + 2] = sv * 0.125f; kt[jj][64 + q * 4 + 2] = cv * 0.125f;
      sincosf(pv.w, &sv, &cv);
      kt[jj][q * 4 + 3] = sv * 0.125f; kt[jj][64 + q * 4 + 3] = cv * 0.125f;
      const unsigned short* vp = Vb + row * EE + h * DD + q * 8;
      ushort4 v0 = *(const ushort4*)vp;
      ushort4 v1 = *(const ushort4*)(vp + 4);
      vt[jj][q * 8 + 0] = b2f(v0.x); vt[jj][q * 8 + 1] = b2f(v0.y);
      vt[jj][q * 8 + 2] = b2f(v0.z); vt[jj][q * 8 + 3] = b2f(v0.w);
      vt[jj][q * 8 + 4] = b2f(v1.x); vt[jj][q * 8 + 5] = b2f(v1.y);
      vt[jj][q * 8 + 6] = b2f(v1.z); vt[jj][q * 8 + 7] = b2f(v1.w);
    }
    __syncthreads();
#pragma unroll
    for (int jj = 0; jj < 16; ++jj) {
      float a[8], bb[8];
      *(float4*)&a[0] = *(const float4*)&kt[jj][ty * 8];
      *(float4*)&a[4] = *(const float4*)&kt[jj][ty * 8 + 4];
      *(float4*)&bb[0] = *(const float4*)&vt[jj][tx * 8];
      *(float4*)&bb[4] = *(const float4*)&vt[jj][tx * 8 + 4];
#pragma unroll
      for (int i = 0; i < 8; ++i)
#pragma unroll
        for (int j = 0; j < 8; ++j)
          acc[i][j] = fmaf(a[i], bb[j], acc[i][j]);
      if (tx == 0) {
#pragma unroll
        for (int i = 0; i < 8; ++i) zacc[i] += a[i];
      }
    }
  }
  const int bh = b * HH + h;
  unsigned short* sp = Sb + ((size_t)bh * NC + c) * (CH * DD);
#pragma unroll
  for (int i = 0; i < 8; ++i) {
    unsigned short* rowp = sp + (ty * 8 + i) * DD + tx * 8;
    ushort4 o0 = make_ushort4(f2b(acc[i][0]), f2b(acc[i][1]), f2b(acc[i][2]), f2b(acc[i][3]));
    ushort4 o1 = make_ushort4(f2b(acc[i][4]), f2b(acc[i][5]), f2b(acc[i][6]), f2b(acc[i][7]));
    *(ushort4*)rowp = o0;
    *(ushort4*)(rowp + 4) = o1;
  }
  if (tx == 0) {
    float* zp = Z + ((size_t)bh * NC + c) * CH + ty * 8;
#pragma unroll
    for (int i = 0; i < 8; ++i) zp[i] = zacc[i];
  }
}

// ---------------- scan: exclusive prefix over chunks (S bf16, Z fp32)
__global__ __launch_bounds__(256) void scan_kernel(unsigned short* __restrict__ Sb,
                                                   float* __restrict__ Z)
{
  int gid = blockIdx.x * 256 + threadIdx.x;
  const int SE = 64 * CH * DD;  // 1048576 scan columns for S
  if (gid < SE) {
    int bh = gid >> 14, fd = gid & 16383;
    unsigned short* p = Sb + (size_t)bh * NC * 16384 + fd;
    float run = 0.f;
#pragma unroll
    for (int cc = 0; cc < NC; ++cc) {
      float t = b2f(p[(size_t)cc * 16384]);
      p[(size_t)cc * 16384] = f2b(run);
      run += t;
    }
  } else {
    int zi = gid - SE;
    if (zi < 64 * CH) {
      int bh = zi >> 7, f = zi & 127;
      float* p = Z + (size_t)bh * NC * CH + f;
      float run = 0.f;
#pragma unroll
      for (int cc = 0; cc < NC; ++cc) {
        float t = p[cc * CH];
        p[cc * CH] = run;
        run += t;
      }
    }
  }
}

// ---------------- attn: per (c,b,h); S,Z hold exclusive prefixes
__global__ __launch_bounds__(256) void attn_kernel(
    const float* __restrict__ Pq, const float* __restrict__ Pk,
    const unsigned short* __restrict__ Vb, const unsigned short* __restrict__ Sb,
    const float* __restrict__ Z, unsigned short* __restrict__ Ob)
{
  __shared__ float sc[128][132];
  __shared__ float tA[16][132];
  __shared__ float tB[16][132];
  __shared__ float den[128];
  __shared__ float zs[128];
  const int c = blockIdx.x, b = blockIdx.y, h = blockIdx.z;
  const int tid = threadIdx.x;
  const int ty = tid >> 4, tx = tid & 15;
  const int bh = b * HH + h;

  if (tid < 128) zs[tid] = Z[((size_t)bh * NC + c) * CH + tid];

  float acc[8][8];
#pragma unroll
  for (int i = 0; i < 8; ++i)
#pragma unroll
    for (int j = 0; j < 8; ++j) acc[i][j] = 0.f;
  float denz[8] = {0.f, 0.f, 0.f, 0.f, 0.f, 0.f, 0.f, 0.f};

  // phase A: scores = phi_q @ phi_k^T over 128 features; denz = phi_q . z
  for (int ft = 0; ft < PHI2; ft += 16) {
    __syncthreads();
    const int cb0 = (ft < 64) ? ft : (ft - 64);
    const bool issin = (ft < 64);
#pragma unroll
    for (int s = 0; s < 2; ++s) {
      int idx = tid + s * 256;
      int i = idx >> 2, fq = idx & 3;
      size_t row = (size_t)((c * CH + i) * BB + b);
      float4 qv = *(const float4*)(Pq + row * NPROJ + h * KK + cb0 + fq * 4);
      float4 kv = *(const float4*)(Pk + row * NPROJ + h * KK + cb0 + fq * 4);
      float sv, cv;
      sincosf(qv.x, &sv, &cv); tA[fq * 4 + 0][i] = (issin ? sv : cv) * 0.125f;
      sincosf(qv.y, &sv, &cv); tA[fq * 4 + 1][i] = (issin ? sv : cv) * 0.125f;
      sincosf(qv.z, &sv, &cv); tA[fq * 4 + 2][i] = (issin ? sv : cv) * 0.125f;
      sincosf(qv.w, &sv, &cv); tA[fq * 4 + 3][i] = (issin ? sv : cv) * 0.125f;
      sincosf(kv.x, &sv, &cv); tB[fq * 4 + 0][i] = (issin ? sv : cv) * 0.125f;
      sincosf(kv.y, &sv, &cv); tB[fq * 4 + 1][i] = (issin ? sv : cv) * 0.125f;
      sincosf(kv.z, &sv, &cv); tB[fq * 4 + 2][i] = (issin ? sv : cv) * 0.125f;
      sincosf(kv.w, &sv, &cv); tB[fq * 4 + 3][i] = (issin ? sv : cv) * 0.125f;
    }
    __syncthreads();
#pragma unroll
    for (int ff = 0; ff < 16; ++ff) {
      float a[8], bb[8];
      *(float4*)&a[0] = *(const float4*)&tA[ff][ty * 8];
      *(float4*)&a[4] = *(const float4*)&tA[ff][ty * 8 + 4];
      *(float4*)&bb[0] = *(const float4*)&tB[ff][tx * 8];
      *(float4*)&bb[4] = *(const float4*)&tB[ff][tx * 8 + 4];
#pragma unroll
      for (int i = 0; i < 8; ++i)
#pragma unroll
        for (int j = 0; j < 8; ++j)
          acc[i][j] = fmaf(a[i], bb[j], acc[i][j]);
      if (tx == 0) {
        float zv = zs[ft + ff];
#pragma unroll
        for (int i = 0; i < 8; ++i) denz[i] = fmaf(a[i], zv, denz[i]);
      }
    }
  }
  __syncthreads();
#pragma unroll
  for (int i = 0; i < 8; ++i) {
    int gi = ty * 8 + i;
#pragma unroll
    for (int j = 0; j < 8; ++j) {
      int gj = tx * 8 + j;
      sc[gi][gj] = (gj <= gi) ? acc[i][j] : 0.f;
    }
  }
  if (tx == 0) {
#pragma unroll
    for (int i = 0; i < 8; ++i) den[ty * 8 + i] = denz[i];
  }
  __syncthreads();
  {
    int i = tid >> 1;
    int j0 = (tid & 1) * 64;
    float ssum = 0.f;
#pragma unroll
    for (int j = 0; j < 64; j += 4) {
      float4 sv = *(const float4*)&sc[i][j0 + j];
      ssum += sv.x + sv.y + sv.z + sv.w;
    }
    ssum += __shfl_xor(ssum, 1);
    if ((tid & 1) == 0) den[i] += ssum;
  }

  // phase B: num = sc @ v + phi_q @ S_prefix
  float nacc[8][8];
#pragma unroll
  for (int i = 0; i < 8; ++i)
#pragma unroll
    for (int j = 0; j < 8; ++j) nacc[i][j] = 0.f;

  for (int jt = 0; jt < CH; jt += 16) {
    __syncthreads();
    {
      int jj = tid >> 4, dq = tid & 15;
      size_t row = (size_t)((c * CH + jt + jj) * BB + b);
      const unsigned short* vp = Vb + row * EE + h * DD + dq * 8;
      ushort4 v0 = *(const ushort4*)vp;
      ushort4 v1 = *(const ushort4*)(vp + 4);
      tB[jj][dq * 8 + 0] = b2f(v0.x); tB[jj][dq * 8 + 1] = b2f(v0.y);
      tB[jj][dq * 8 + 2] = b2f(v0.z); tB[jj][dq * 8 + 3] = b2f(v0.w);
      tB[jj][dq * 8 + 4] = b2f(v1.x); tB[jj][dq * 8 + 5] = b2f(v1.y);
      tB[jj][dq * 8 + 6] = b2f(v1.z); tB[jj][dq * 8 + 7] = b2f(v1.w);
    }
    __syncthreads();
#pragma unroll
    for (int jj = 0; jj < 16; ++jj) {
      int j = jt + jj;
      float a[8], bb[8];
#pragma unroll
      for (int i = 0; i < 8; ++i) a[i] = sc[ty * 8 + i][j];
      *(float4*)&bb[0] = *(const float4*)&tB[jj][tx * 8];
      *(float4*)&bb[4] = *(const float4*)&tB[jj][tx * 8 + 4];
#pragma unroll
      for (int i = 0; i < 8; ++i)
#pragma unroll
        for (int jd = 0; jd < 8; ++jd)
          nacc[i][jd] = fmaf(a[i], bb[jd], nacc[i][jd]);
    }
  }
  const unsigned short* S0 = Sb + ((size_t)bh * NC + c) * (CH * DD);
  for (int ft = 0; ft < PHI2; ft += 16) {
    __syncthreads();
    const int cb0 = (ft < 64) ? ft : (ft - 64);
    const bool issin = (ft < 64);
#pragma unroll
    for (int s = 0; s < 2; ++s) {
      int idx = tid + s * 256;
      int i = idx >> 2, fq = idx & 3;
      size_t row = (size_t)((c * CH + i) * BB + b);
      float4 qv = *(const float4*)(Pq + row * NPROJ + h * KK + cb0 + fq * 4);
      float sv, cv;
      sincosf(qv.x, &sv, &cv); tA[fq * 4 + 0][i] = (issin ? sv : cv) * 0.125f;
      sincosf(qv.y, &sv, &cv); tA[fq * 4 + 1][i] = (issin ? sv : cv) * 0.125f;
      sincosf(qv.z, &sv, &cv); tA[fq * 4 + 2][i] = (issin ? sv : cv) * 0.125f;
      sincosf(qv.w, &sv, &cv); tA[fq * 4 + 3][i] = (issin ? sv : cv) * 0.125f;
      int jj = idx >> 5, d = (idx & 31) * 4;
      ushort4 s4v = *(const ushort4*)(S0 + (size_t)(ft + jj) * DD + d);
      tB[jj][d + 0] = b2f(s4v.x); tB[jj][d + 1] = b2f(s4v.y);
      tB[jj][d + 2] = b2f(s4v.z); tB[jj][d + 3] = b2f(s4v.w);
    }
    __syncthreads();
#pragma unroll
    for (int ff = 0; ff < 16; ++ff) {
      float a[8], bb[8];
      *(float4*)&a[0] = *(const float4*)&tA[ff][ty * 8];
      *(float4*)&a[4] = *(const float4*)&tA[ff][ty * 8 + 4];
      *(float4*)&bb[0] = *(const float4*)&tB[ff][tx * 8];
      *(float4*)&bb[4] = *(const float4*)&tB[ff][tx * 8 + 4];
#pragma unroll
      for (int i = 0; i < 8; ++i)
#pragma unroll
        for (int jd = 0; jd < 8; ++jd)
          nacc[i][jd] = fmaf(a[i], bb[jd], nacc[i][jd]);
    }
  }
#pragma unroll
  for (int i = 0; i < 8; ++i) {
    int gi = ty * 8 + i;
    float inv = 1.0f / fmaxf(den[gi], EPSV);
    unsigned short* op = Ob + (size_t)((c * CH + gi) * BB + b) * EE + h * DD + tx * 8;
    ushort4 o0 = make_ushort4(f2b(nacc[i][0] * inv), f2b(nacc[i][1] * inv),
                              f2b(nacc[i][2] * inv), f2b(nacc[i][3] * inv));
    ushort4 o1 = make_ushort4(f2b(nacc[i][4] * inv), f2b(nacc[i][5] * inv),
                              f2b(nacc[i][6] * inv), f2b(nacc[i][7] * inv));
    *(ushort4*)op = o0;
    *(ushort4*)(op + 4) = o1;
  }
}

extern "C" void kernel_launch(void* const* d_in, const int* in_sizes, int n_in,
                              void* d_out, int out_size, void* d_ws, size_t ws_size,
                              hipStream_t stream)
{
  const float* x     = (const float*)d_in[0];
  const float* rmat  = (const float*)d_in[1];
  const float* Wq    = (const float*)d_in[2];
  const float* bq    = (const float*)d_in[3];
  const float* Wk    = (const float*)d_in[4];
  const float* bk    = (const float*)d_in[5];
  const float* Wv    = (const float*)d_in[6];
  const float* bv    = (const float*)d_in[7];
  const float* Wo    = (const float*)d_in[8];
  const float* bo    = (const float*)d_in[9];
  const float* sigma = (const float*)d_in[10];
  float* out = (float*)d_out;

  // workspace layout (256 MiB total):
  //   [0,   64M): pq_p  fp32 (NROWS x 512 pre-sincos q proj)
  //   [64, 128M): pk_p  fp32
  //   [128,192M): Vb    bf16 (NROWS x 1024)
  //   [192,256M): Ob    bf16 (NROWS x 1024); Weff/beff alias here (dead before attn)
  // d_out reused as scratch (dead before final GEMM overwrites):
  //   [0,  64M): Sb bf16 (64 bh x 32 chunks x 128f x 128d)
  //   [64, 65M): Z  fp32 (64 bh x 32 chunks x 128f)
  float* ws_f = (float*)d_ws;
  float* pq_p = ws_f;
  float* pk_p = ws_f + (size_t)16777216;
  unsigned short* Vb = (unsigned short*)((char*)d_ws + (size_t)128 * 1024 * 1024);
  unsigned short* Ob = (unsigned short*)((char*)d_ws + (size_t)192 * 1024 * 1024);
  float* Weq = (float*)Ob;
  float* Wek = Weq + 524288;
  float* beq = Wek + 524288;
  float* bek = beq + 512;
  unsigned short* Sb = (unsigned short*)d_out;
  float* Zf = (float*)((char*)d_out + (size_t)64 * 1024 * 1024);

  dim3 bt(256);
  hipLaunchKernelGGL(weff_kernel, dim3(8, 8), bt, 0, stream, rmat, sigma, Wq, bq, Weq, beq);
  hipLaunchKernelGGL(weff_kernel, dim3(8, 8), bt, 0, stream, rmat, sigma, Wk, bk, Wek, bek);
  hipLaunchKernelGGL(gemm_nt, dim3(NROWS / 128, NPROJ / 128), bt, 0, stream,
                     x, Weq, beq, pq_p, NROWS, NPROJ, EE);
  hipLaunchKernelGGL(gemm_nt, dim3(NROWS / 128, NPROJ / 128), bt, 0, stream,
                     x, Wek, bek, pk_p, NROWS, NPROJ, EE);
  hipLaunchKernelGGL(gemm_nt_b16out, dim3(NROWS / 128, EE / 128), bt, 0, stream,
                     x, Wv, bv, Vb, NROWS, EE, EE);
  hipLaunchKernelGGL(pass1_kernel, dim3(NC, BB, HH), bt, 0, stream, pk_p, Vb, Sb, Zf);
  hipLaunchKernelGGL(scan_kernel, dim3((64 * CH * DD + 64 * CH + 255) / 256), bt, 0, stream, Sb, Zf);
  hipLaunchKernelGGL(attn_kernel, dim3(NC, BB, HH), bt, 0, stream, pq_p, pk_p, Vb, Sb, Zf, Ob);
  hipLaunchKernelGGL(gemm_nt_a16, dim3(NROWS / 128, EE / 128), bt, 0, stream,
                     Ob, Wo, bo, out, NROWS, EE, EE);
}